// Round 1
// baseline (2018.446 us; speedup 1.0000x reference)
//
#include <hip/hip_runtime.h>
#include <hip/hip_bf16.h>

#define B_  2
#define S_  2048
#define D_  1024
#define H_  16
#define DH_ 64
#define M_  (B_ * S_)   // 4096

// ---------------- Generic tiled fp32 GEMM with bias ----------------
// C[M,N] = A[M,K] @ B[K,N] + bias[N]; A,B,C row-major.
// BM=BN=64, BK=16, 256 threads, each thread computes a 4x4 micro-tile.
template<int BM, int BN, int BK>
__global__ __launch_bounds__(256) void gemm_bias(
    const float* __restrict__ A, const float* __restrict__ Bm,
    const float* __restrict__ bias, float* __restrict__ C,
    int N, int K) {
  __shared__ float As[BM][BK + 1];
  __shared__ float Bs[BK][BN + 1];
  const int t  = threadIdx.x;
  const int tr = t / 16, tc = t % 16;        // 16x16 thread grid
  const int row0 = blockIdx.y * BM;
  const int col0 = blockIdx.x * BN;

  float acc[4][4] = {};

  for (int k0 = 0; k0 < K; k0 += BK) {
    // load A tile: BM x BK (64*16 = 1024 elems, 4/thread)
    {
      const int r = t / BK, c = t % BK;
      #pragma unroll
      for (int i = 0; i < (BM * BK) / 256; ++i)
        As[r + i * (256 / BK)][c] = A[(size_t)(row0 + r + i * (256 / BK)) * K + k0 + c];
    }
    // load B tile: BK x BN
    {
      const int r = t / BN, c = t % BN;
      #pragma unroll
      for (int i = 0; i < (BK * BN) / 256; ++i)
        Bs[r + i * (256 / BN)][c] = Bm[(size_t)(k0 + r + i * (256 / BN)) * N + col0 + c];
    }
    __syncthreads();
    #pragma unroll
    for (int kk = 0; kk < BK; ++kk) {
      float a[4], b[4];
      #pragma unroll
      for (int i = 0; i < 4; ++i) a[i] = As[tr * 4 + i][kk];
      #pragma unroll
      for (int j = 0; j < 4; ++j) b[j] = Bs[kk][tc * 4 + j];
      #pragma unroll
      for (int i = 0; i < 4; ++i)
        #pragma unroll
        for (int j = 0; j < 4; ++j)
          acc[i][j] += a[i] * b[j];
    }
    __syncthreads();
  }

  #pragma unroll
  for (int i = 0; i < 4; ++i) {
    const int row = row0 + tr * 4 + i;
    #pragma unroll
    for (int j = 0; j < 4; ++j) {
      const int col = col0 + tc * 4 + j;
      C[(size_t)row * N + col] = acc[i][j] + bias[col];
    }
  }
}

// ---------------- Causal flash attention ----------------
// qkv: [B*S, 3*D] rows; Q at col h*64, K at 1024 + h*64, V at 2048 + h*64.
// Output attn: [B*S, D] with col h*64+d  (== transpose(0,2,1,3).reshape).
// grid: (S/64, B*H), block 256. Each block does 64 q-rows for one (b,h).
__global__ __launch_bounds__(256) void attn_fwd(
    const float* __restrict__ qkv, float* __restrict__ attn_out) {
  const int bh = blockIdx.y;
  const int b = bh / H_, h = bh % H_;
  const int q0 = blockIdx.x * 64;
  const float* base = qkv + (size_t)b * S_ * (3 * D_);

  __shared__ float Qs[64][65];
  __shared__ float Ks[64][65];
  __shared__ float Vs[64][65];
  __shared__ float Ps[64][65];

  const int t  = threadIdx.x;
  const int tr = t / 16, tc = t % 16;

  // load Q tile (coalesced: 64 consecutive floats per row chunk)
  #pragma unroll
  for (int i = 0; i < 16; ++i) {
    const int r = t / 64 + i * 4, c = t % 64;
    Qs[r][c] = base[(size_t)(q0 + r) * (3 * D_) + h * DH_ + c];
  }

  float m_run[4], l_run[4], O[4][4];
  #pragma unroll
  for (int i = 0; i < 4; ++i) {
    m_run[i] = -1e30f; l_run[i] = 0.f;
    #pragma unroll
    for (int j = 0; j < 4; ++j) O[i][j] = 0.f;
  }
  const float scale = 0.125f;  // 1/sqrt(64)

  const int ktiles = blockIdx.x + 1;  // causal: only tiles with k0 <= q0+63
  for (int kt = 0; kt < ktiles; ++kt) {
    const int k0 = kt * 64;
    __syncthreads();  // previous iteration's Ps/Vs reads done (also orders Qs)
    #pragma unroll
    for (int i = 0; i < 16; ++i) {
      const int r = t / 64 + i * 4, c = t % 64;
      Ks[r][c] = base[(size_t)(k0 + r) * (3 * D_) + D_ + h * DH_ + c];
      Vs[r][c] = base[(size_t)(k0 + r) * (3 * D_) + 2 * D_ + h * DH_ + c];
    }
    __syncthreads();

    // scores: S[r][c] = sum_d Qs[r][d] * Ks[c][d]
    float sc[4][4] = {};
    #pragma unroll
    for (int d = 0; d < DH_; ++d) {
      float a[4], bb[4];
      #pragma unroll
      for (int i = 0; i < 4; ++i) a[i] = Qs[tr * 4 + i][d];
      #pragma unroll
      for (int j = 0; j < 4; ++j) bb[j] = Ks[tc * 4 + j][d];
      #pragma unroll
      for (int i = 0; i < 4; ++i)
        #pragma unroll
        for (int j = 0; j < 4; ++j) sc[i][j] += a[i] * bb[j];
    }
    // scale + causal mask
    #pragma unroll
    for (int i = 0; i < 4; ++i) {
      const int q = q0 + tr * 4 + i;
      #pragma unroll
      for (int j = 0; j < 4; ++j) {
        const int k = k0 + tc * 4 + j;
        sc[i][j] = (k <= q) ? sc[i][j] * scale : -1e30f;
      }
    }
    // online softmax: row reductions across the 16 tc-lanes
    float alpha[4];
    #pragma unroll
    for (int i = 0; i < 4; ++i) {
      float v = fmaxf(fmaxf(sc[i][0], sc[i][1]), fmaxf(sc[i][2], sc[i][3]));
      #pragma unroll
      for (int off = 1; off < 16; off <<= 1) v = fmaxf(v, __shfl_xor(v, off));
      const float mnew = fmaxf(m_run[i], v);
      alpha[i] = __expf(m_run[i] - mnew);
      m_run[i] = mnew;
    }
    #pragma unroll
    for (int i = 0; i < 4; ++i) {
      float s = 0.f;
      #pragma unroll
      for (int j = 0; j < 4; ++j) {
        const float p = __expf(sc[i][j] - m_run[i]);
        sc[i][j] = p;
        s += p;
      }
      #pragma unroll
      for (int off = 1; off < 16; off <<= 1) s += __shfl_xor(s, off);
      l_run[i] = l_run[i] * alpha[i] + s;
    }
    // stage P, rescale O
    #pragma unroll
    for (int i = 0; i < 4; ++i)
      #pragma unroll
      for (int j = 0; j < 4; ++j) {
        Ps[tr * 4 + i][tc * 4 + j] = sc[i][j];
        O[i][j] *= alpha[i];
      }
    __syncthreads();
    // O[r][c] += sum_k Ps[r][k] * Vs[k][c]  (thread cols c = tc*4+j)
    #pragma unroll
    for (int k = 0; k < 64; ++k) {
      float p[4], vv[4];
      #pragma unroll
      for (int i = 0; i < 4; ++i) p[i] = Ps[tr * 4 + i][k];
      #pragma unroll
      for (int j = 0; j < 4; ++j) vv[j] = Vs[k][tc * 4 + j];
      #pragma unroll
      for (int i = 0; i < 4; ++i)
        #pragma unroll
        for (int j = 0; j < 4; ++j) O[i][j] += p[i] * vv[j];
    }
  }

  #pragma unroll
  for (int i = 0; i < 4; ++i) {
    const int r = tr * 4 + i;
    const float inv = 1.0f / l_run[i];
    #pragma unroll
    for (int j = 0; j < 4; ++j) {
      const int c = tc * 4 + j;
      attn_out[(size_t)(b * S_ + q0 + r) * D_ + h * DH_ + c] = O[i][j] * inv;
    }
  }
}

extern "C" void kernel_launch(void* const* d_in, const int* in_sizes, int n_in,
                              void* d_out, int out_size, void* d_ws, size_t ws_size,
                              hipStream_t stream) {
  const float* x     = (const float*)d_in[0];
  const float* W_qkv = (const float*)d_in[1];
  const float* b_qkv = (const float*)d_in[2];
  const float* W_out = (const float*)d_in[3];
  const float* b_out = (const float*)d_in[4];
  float* out = (float*)d_out;

  float* qkv  = (float*)d_ws;                      // [4096, 3072] = 50.3 MB
  float* attn = qkv + (size_t)M_ * (3 * D_);       // [4096, 1024] = 16.8 MB

  dim3 blk(256);
  // 1) QKV projection
  gemm_bias<64, 64, 16><<<dim3((3 * D_) / 64, M_ / 64), blk, 0, stream>>>(
      x, W_qkv, b_qkv, qkv, 3 * D_, D_);
  // 2) causal attention
  attn_fwd<<<dim3(S_ / 64, B_ * H_), blk, 0, stream>>>(qkv, attn);
  // 3) output projection
  gemm_bias<64, 64, 16><<<dim3(D_ / 64, M_ / 64), blk, 0, stream>>>(
      attn, W_out, b_out, out, D_, D_);
}

// Round 2
// 892.893 us; speedup vs baseline: 2.2606x; 2.2606x over previous
//
#include <hip/hip_runtime.h>
#include <hip/hip_bf16.h>

#define B_  2
#define S_  2048
#define D_  1024
#define H_  16
#define DH_ 64
#define M_  (B_ * S_)   // 4096

typedef __bf16 bf16x8 __attribute__((ext_vector_type(8)));
typedef float  f32x4  __attribute__((ext_vector_type(4)));
typedef unsigned short us4 __attribute__((ext_vector_type(4)));

__device__ inline unsigned short f2bf(float f) {
  union { __bf16 h; unsigned short u; } cv;
  cv.h = (__bf16)f;
  return cv.u;
}

// ---------------- Generic tiled fp32 GEMM with bias ----------------
template<int BM, int BN, int BK>
__global__ __launch_bounds__(256) void gemm_bias(
    const float* __restrict__ A, const float* __restrict__ Bm,
    const float* __restrict__ bias, float* __restrict__ C,
    int N, int K) {
  __shared__ float As[BM][BK + 1];
  __shared__ float Bs[BK][BN + 1];
  const int t  = threadIdx.x;
  const int tr = t / 16, tc = t % 16;
  const int row0 = blockIdx.y * BM;
  const int col0 = blockIdx.x * BN;

  float acc[4][4] = {};

  for (int k0 = 0; k0 < K; k0 += BK) {
    {
      const int r = t / BK, c = t % BK;
      #pragma unroll
      for (int i = 0; i < (BM * BK) / 256; ++i)
        As[r + i * (256 / BK)][c] = A[(size_t)(row0 + r + i * (256 / BK)) * K + k0 + c];
    }
    {
      const int r = t / BN, c = t % BN;
      #pragma unroll
      for (int i = 0; i < (BK * BN) / 256; ++i)
        Bs[r + i * (256 / BN)][c] = Bm[(size_t)(k0 + r + i * (256 / BN)) * N + col0 + c];
    }
    __syncthreads();
    #pragma unroll
    for (int kk = 0; kk < BK; ++kk) {
      float a[4], b[4];
      #pragma unroll
      for (int i = 0; i < 4; ++i) a[i] = As[tr * 4 + i][kk];
      #pragma unroll
      for (int j = 0; j < 4; ++j) b[j] = Bs[kk][tc * 4 + j];
      #pragma unroll
      for (int i = 0; i < 4; ++i)
        #pragma unroll
        for (int j = 0; j < 4; ++j)
          acc[i][j] += a[i] * b[j];
    }
    __syncthreads();
  }

  #pragma unroll
  for (int i = 0; i < 4; ++i) {
    const int row = row0 + tr * 4 + i;
    #pragma unroll
    for (int j = 0; j < 4; ++j) {
      const int col = col0 + tc * 4 + j;
      C[(size_t)row * N + col] = acc[i][j] + bias[col];
    }
  }
}

// ---------------- Causal flash attention, bf16 MFMA ----------------
// qkv fp32: [B*S, 3*D]; Q at col h*64, K at D+h*64, V at 2D+h*64.
// Output attn fp32: [B*S, D] at col h*64+d.
// grid: (S/64, B*H), block 256 = 4 waves; wave w owns q rows qw0..qw0+15.
__global__ __launch_bounds__(256) void attn_fwd_mfma(
    const float* __restrict__ qkv, float* __restrict__ attn_out) {
  const int bh = blockIdx.y;
  const int b = bh / H_, h = bh % H_;
  const int q0 = blockIdx.x * 64;
  const float* base = qkv + (size_t)b * S_ * (3 * D_);

  // bf16 tiles, 128 B per row, XOR-swizzled (byte ^= (row&7)<<4)
  __shared__ __align__(16) char smK[64 * 128];  // K tile row-major [k][d]
  __shared__ __align__(16) char smV[64 * 128];  // V^T tile [d][k]
  __shared__ __align__(16) char smP[64 * 128];  // P tile [q][k], wave-private rows

  const int t  = threadIdx.x;
  const int w  = t >> 6;        // wave id
  const int l  = t & 63;        // lane
  const int lg = l >> 4;        // 0..3 (K-chunk group)
  const int lr = l & 15;        // 0..15 (row/col within fragment)
  const int qw0 = q0 + w * 16;  // wave's first q row

  // ---- Q fragments (pre-scaled by 1/sqrt(64)), registers ----
  bf16x8 qf[2];
  {
    const float* qp = base + (size_t)(qw0 + lr) * (3 * D_) + h * DH_ + 8 * lg;
    #pragma unroll
    for (int ks = 0; ks < 2; ++ks) {
      float4 a = *(const float4*)(qp + 32 * ks);
      float4 c = *(const float4*)(qp + 32 * ks + 4);
      qf[ks][0] = (__bf16)(a.x * 0.125f);
      qf[ks][1] = (__bf16)(a.y * 0.125f);
      qf[ks][2] = (__bf16)(a.z * 0.125f);
      qf[ks][3] = (__bf16)(a.w * 0.125f);
      qf[ks][4] = (__bf16)(c.x * 0.125f);
      qf[ks][5] = (__bf16)(c.y * 0.125f);
      qf[ks][6] = (__bf16)(c.z * 0.125f);
      qf[ks][7] = (__bf16)(c.w * 0.125f);
    }
  }

  float mrun[4], lrun[4];
  f32x4 acc_o[4] = {};
  #pragma unroll
  for (int r = 0; r < 4; ++r) { mrun[r] = -1e30f; lrun[r] = 0.f; }

  const int ntiles = blockIdx.x + 1;  // causal: k0 <= q0+63
  for (int kti = 0; kti < ntiles; ++kti) {
    const int k0 = kti * 64;
    __syncthreads();  // previous tile's K/V fragment reads complete

    // ---- stage K tile (coalesced rows -> bf16, swizzled) ----
    #pragma unroll
    for (int it = 0; it < 4; ++it) {
      int idx = t + it * 256;
      int r = idx >> 4, c4 = idx & 15;
      float4 kvv = *(const float4*)(base + (size_t)(k0 + r) * (3 * D_) + D_ + h * DH_ + c4 * 4);
      us4 p = { f2bf(kvv.x), f2bf(kvv.y), f2bf(kvv.z), f2bf(kvv.w) };
      *(us4*)(smK + r * 128 + ((c4 * 8) ^ ((r & 7) << 4))) = p;
    }
    // ---- stage V^T tile (strided global read, conflict-free LDS write) ----
    {
      int k = t & 63;  // lane == source row -> contiguous column writes
      #pragma unroll
      for (int it = 0; it < 4; ++it) {
        int c4 = (t >> 6) + it * 4;
        float4 vv = *(const float4*)(base + (size_t)(k0 + k) * (3 * D_) + 2 * D_ + h * DH_ + c4 * 4);
        float vf[4] = { vv.x, vv.y, vv.z, vv.w };
        #pragma unroll
        for (int j = 0; j < 4; ++j) {
          int row = c4 * 4 + j;
          *(unsigned short*)(smV + row * 128 + ((2 * k) ^ ((row & 7) << 4))) = f2bf(vf[j]);
        }
      }
    }
    __syncthreads();

    if (k0 > qw0 + 15) continue;  // fully masked for this wave (no barriers below)

    // ---- QK^T: sc[kt] = Q(16x64) . K^T(64x16kt) ----
    f32x4 sc[4] = {};
    #pragma unroll
    for (int kt = 0; kt < 4; ++kt) {
      #pragma unroll
      for (int ks = 0; ks < 2; ++ks) {
        int row = kt * 16 + lr;
        bf16x8 kb = *(const bf16x8*)(smK + row * 128 + (((ks * 64) + 16 * lg) ^ ((row & 7) << 4)));
        sc[kt] = __builtin_amdgcn_mfma_f32_16x16x32_bf16(qf[ks], kb, sc[kt], 0, 0, 0);
      }
    }

    // ---- causal mask (only near the diagonal) ----
    if (k0 + 63 > qw0) {
      #pragma unroll
      for (int kt = 0; kt < 4; ++kt) {
        int kc = k0 + kt * 16 + lr;
        #pragma unroll
        for (int r = 0; r < 4; ++r)
          if (kc > qw0 + lg * 4 + r) sc[kt][r] = -1e30f;
      }
    }

    // ---- online softmax: rows live in 16-lane groups (same lg) ----
    float mnew[4], alpha[4];
    #pragma unroll
    for (int r = 0; r < 4; ++r) {
      float v = fmaxf(fmaxf(sc[0][r], sc[1][r]), fmaxf(sc[2][r], sc[3][r]));
      #pragma unroll
      for (int off = 1; off < 16; off <<= 1) v = fmaxf(v, __shfl_xor(v, off));
      mnew[r] = fmaxf(mrun[r], v);
      alpha[r] = __expf(mrun[r] - mnew[r]);
      mrun[r] = mnew[r];
    }
    #pragma unroll
    for (int r = 0; r < 4; ++r) {
      float s = 0.f;
      #pragma unroll
      for (int kt = 0; kt < 4; ++kt) {
        float p = __expf(sc[kt][r] - mnew[r]);
        sc[kt][r] = p;
        s += p;
      }
      #pragma unroll
      for (int off = 1; off < 16; off <<= 1) s += __shfl_xor(s, off);
      lrun[r] = lrun[r] * alpha[r] + s;
    }

    // ---- write P (bf16) to wave-private LDS rows; rescale O ----
    #pragma unroll
    for (int kt = 0; kt < 4; ++kt) {
      #pragma unroll
      for (int r = 0; r < 4; ++r) {
        int row = w * 16 + lg * 4 + r;
        *(unsigned short*)(smP + row * 128 + ((2 * (kt * 16 + lr)) ^ ((row & 7) << 4))) =
            f2bf(sc[kt][r]);
      }
    }
    #pragma unroll
    for (int dt = 0; dt < 4; ++dt)
      #pragma unroll
      for (int r = 0; r < 4; ++r) acc_o[dt][r] *= alpha[r];

    // ---- PV: A = P fragments (wave-private, lgkmcnt-ordered), B = V^T ----
    bf16x8 pa[2];
    #pragma unroll
    for (int ks = 0; ks < 2; ++ks) {
      int row = w * 16 + lr;
      pa[ks] = *(const bf16x8*)(smP + row * 128 + (((ks * 64) + 16 * lg) ^ ((lr & 7) << 4)));
    }
    #pragma unroll
    for (int dt = 0; dt < 4; ++dt) {
      #pragma unroll
      for (int ks = 0; ks < 2; ++ks) {
        int row = dt * 16 + lr;
        bf16x8 vb = *(const bf16x8*)(smV + row * 128 + (((ks * 64) + 16 * lg) ^ ((row & 7) << 4)));
        acc_o[dt] = __builtin_amdgcn_mfma_f32_16x16x32_bf16(pa[ks], vb, acc_o[dt], 0, 0, 0);
      }
    }
  }

  // ---- normalize and write out (fp32) ----
  float inv[4];
  #pragma unroll
  for (int r = 0; r < 4; ++r) inv[r] = 1.0f / lrun[r];
  #pragma unroll
  for (int dt = 0; dt < 4; ++dt) {
    #pragma unroll
    for (int r = 0; r < 4; ++r) {
      attn_out[(size_t)(b * S_ + qw0 + lg * 4 + r) * D_ + h * DH_ + dt * 16 + lr] =
          acc_o[dt][r] * inv[r];
    }
  }
}

extern "C" void kernel_launch(void* const* d_in, const int* in_sizes, int n_in,
                              void* d_out, int out_size, void* d_ws, size_t ws_size,
                              hipStream_t stream) {
  const float* x     = (const float*)d_in[0];
  const float* W_qkv = (const float*)d_in[1];
  const float* b_qkv = (const float*)d_in[2];
  const float* W_out = (const float*)d_in[3];
  const float* b_out = (const float*)d_in[4];
  float* out = (float*)d_out;

  float* qkv  = (float*)d_ws;                      // [4096, 3072]
  float* attn = qkv + (size_t)M_ * (3 * D_);       // [4096, 1024]

  dim3 blk(256);
  gemm_bias<64, 64, 16><<<dim3((3 * D_) / 64, M_ / 64), blk, 0, stream>>>(
      x, W_qkv, b_qkv, qkv, 3 * D_, D_);
  attn_fwd_mfma<<<dim3(S_ / 64, B_ * H_), blk, 0, stream>>>(qkv, attn);
  gemm_bias<64, 64, 16><<<dim3(D_ / 64, M_ / 64), blk, 0, stream>>>(
      attn, W_out, b_out, out, D_, D_);
}

// Round 4
// 210.210 us; speedup vs baseline: 9.6020x; 4.2476x over previous
//
#include <hip/hip_runtime.h>
#include <hip/hip_bf16.h>

#define B_  2
#define S_  2048
#define D_  1024
#define H_  16
#define DH_ 64
#define M_  (B_ * S_)       // 4096
#define QKV_LD (3 * D_)     // 3072

typedef __bf16 bf16x8 __attribute__((ext_vector_type(8)));
typedef float  f32x4  __attribute__((ext_vector_type(4)));
typedef unsigned short us4 __attribute__((ext_vector_type(4)));
typedef unsigned short us8 __attribute__((ext_vector_type(8)));

__device__ inline unsigned short f2bf(float f) {
  union { __bf16 h; unsigned short u; } cv; cv.h = (__bf16)f; return cv.u;
}
__device__ inline float bf2f(unsigned short u) {
  union { unsigned int i; float f; } cv; cv.i = ((unsigned int)u) << 16; return cv.f;
}
// typed stores: bf16 does the BIT conversion (round-3 bug: (unsigned short)v
// was an int conversion -> output was all-zero)
__device__ inline void cstore(float* p, float v) { *p = v; }
__device__ inline void cstore(unsigned short* p, float v) { *p = f2bf(v); }

__device__ inline void gload_lds16(const void* g, void* lds) {
  __builtin_amdgcn_global_load_lds(
      (const __attribute__((address_space(1))) unsigned int*)g,
      (__attribute__((address_space(3))) unsigned int*)lds, 16, 0, 0);
}

// ---------------- prep: fp32 -> bf16 (row-major copy) ----------------
__global__ __launch_bounds__(256) void conv_bf16(const float* __restrict__ in,
                                                 unsigned short* __restrict__ out, int n4) {
  int i = blockIdx.x * 256 + threadIdx.x;
  if (i >= n4) return;
  float4 v = ((const float4*)in)[i];
  us4 p = { f2bf(v.x), f2bf(v.y), f2bf(v.z), f2bf(v.w) };
  ((us4*)out)[i] = p;
}

// ---------------- prep: fp32 [K][N] -> bf16 [N][K] transpose ----------------
__global__ __launch_bounds__(256) void transpose_bf16(const float* __restrict__ W,
                                                      unsigned short* __restrict__ Wt,
                                                      int K, int N) {
  __shared__ float tile[32][33];
  const int t = threadIdx.x, tx = t & 31, ty = t >> 5;  // ty 0..7
  const int c0 = blockIdx.x * 32, r0 = blockIdx.y * 32;
  #pragma unroll
  for (int i = 0; i < 4; ++i)
    tile[ty + 8 * i][tx] = W[(size_t)(r0 + ty + 8 * i) * N + c0 + tx];
  __syncthreads();
  #pragma unroll
  for (int i = 0; i < 4; ++i)
    Wt[(size_t)(c0 + ty + 8 * i) * K + r0 + tx] = f2bf(tile[tx][ty + 8 * i]);
}

// ---------------- bf16 MFMA GEMM (m97 structure) ----------------
// C[M,N] = A[M,K] @ Bt[N,K]^T + bias.  128x128 tile, BK=32, 4 waves.
template<typename CT>
__global__ __launch_bounds__(256) void gemm_bf16_tn(
    const unsigned short* __restrict__ A,   // [M][K] bf16
    const unsigned short* __restrict__ Bt,  // [N][K] bf16
    const float* __restrict__ bias,
    CT* __restrict__ C, int N, int K) {
  __shared__ __align__(16) unsigned short smA[128 * 32];
  __shared__ __align__(16) unsigned short smB[128 * 32];
  const int t = threadIdx.x;
  const int w = t >> 6, l = t & 63;
  const int lg = l >> 4, lr = l & 15;
  const int row0 = blockIdx.y * 128, col0 = blockIdx.x * 128;
  const int wm = (w >> 1) * 64, wn = (w & 1) * 64;

  f32x4 acc[4][4] = {};

  for (int k0 = 0; k0 < K; k0 += 32) {
    __syncthreads();  // previous iteration's fragment reads complete
    #pragma unroll
    for (int i = 0; i < 2; ++i) {
      const int inst = 2 * w + i;
      const int r = inst * 16 + (l >> 2);
      const int cb = (l & 3) * 8;  // k-chunk of 8 bf16
      gload_lds16(A  + (size_t)(row0 + r) * K + k0 + cb, &smA[inst * 512]);
      gload_lds16(Bt + (size_t)(col0 + r) * K + k0 + cb, &smB[inst * 512]);
    }
    __syncthreads();  // waits vmcnt(0): tiles resident

    bf16x8 af[4], bfr[4];
    #pragma unroll
    for (int m = 0; m < 4; ++m)
      af[m] = *(const bf16x8*)&smA[(wm + m * 16 + lr) * 32 + lg * 8];
    #pragma unroll
    for (int n = 0; n < 4; ++n)
      bfr[n] = *(const bf16x8*)&smB[(wn + n * 16 + lr) * 32 + lg * 8];
    #pragma unroll
    for (int m = 0; m < 4; ++m)
      #pragma unroll
      for (int n = 0; n < 4; ++n)
        acc[m][n] = __builtin_amdgcn_mfma_f32_16x16x32_bf16(af[m], bfr[n], acc[m][n], 0, 0, 0);
  }

  #pragma unroll
  for (int m = 0; m < 4; ++m) {
    #pragma unroll
    for (int n = 0; n < 4; ++n) {
      const int col = col0 + wn + n * 16 + lr;
      const float bv = bias[col];
      #pragma unroll
      for (int r = 0; r < 4; ++r) {
        const int row = row0 + wm + m * 16 + lg * 4 + r;
        cstore(&C[(size_t)row * N + col], acc[m][n][r] + bv);
      }
    }
  }
}

// ---------------- Causal flash attention, bf16 MFMA, bf16 I/O ----------------
__global__ __launch_bounds__(256) void attn_fwd_mfma(
    const unsigned short* __restrict__ qkv, unsigned short* __restrict__ attn_out) {
  const int bh = blockIdx.y;
  const int b = bh / H_, h = bh % H_;
  const int q0 = blockIdx.x * 64;
  const unsigned short* base = qkv + (size_t)b * S_ * QKV_LD;

  __shared__ __align__(16) char smK[64 * 128];  // K tile [k][d] bf16, XOR-swizzled
  __shared__ __align__(16) char smV[64 * 128];  // V^T tile [d][k]
  __shared__ __align__(16) char smP[64 * 128];  // P tile [q][k], wave-private rows

  const int t  = threadIdx.x;
  const int w  = t >> 6;
  const int l  = t & 63;
  const int lg = l >> 4;
  const int lr = l & 15;
  const int qw0 = q0 + w * 16;

  // Q fragments (pre-scaled by 1/8), registers
  bf16x8 qf[2];
  {
    const unsigned short* qp = base + (size_t)(qw0 + lr) * QKV_LD + h * DH_ + 8 * lg;
    #pragma unroll
    for (int ks = 0; ks < 2; ++ks) {
      us8 qv = *(const us8*)(qp + 32 * ks);
      #pragma unroll
      for (int e = 0; e < 8; ++e) qf[ks][e] = (__bf16)(bf2f(qv[e]) * 0.125f);
    }
  }

  float mrun[4], lrun[4];
  f32x4 acc_o[4] = {};
  #pragma unroll
  for (int r = 0; r < 4; ++r) { mrun[r] = -1e30f; lrun[r] = 0.f; }

  const unsigned short* kbase = base + D_ + h * DH_;
  const unsigned short* vbase = base + 2 * D_ + h * DH_;

  const int ntiles = blockIdx.x + 1;
  for (int kti = 0; kti < ntiles; ++kti) {
    const int k0 = kti * 64;
    __syncthreads();

    // stage K tile: 2 iters x 256 threads x 16B
    #pragma unroll
    for (int it = 0; it < 2; ++it) {
      int idx = t + it * 256;
      int r = idx >> 3, c = idx & 7;
      us8 kv = *(const us8*)(kbase + (size_t)(k0 + r) * QKV_LD + c * 8);
      *(us8*)(smK + r * 128 + ((c * 16) ^ ((r & 7) << 4))) = kv;
    }
    // stage V^T tile
    {
      int k = t & 63;
      #pragma unroll
      for (int it = 0; it < 2; ++it) {
        int ch = (t >> 6) + it * 4;
        us8 vv = *(const us8*)(vbase + (size_t)(k0 + k) * QKV_LD + ch * 8);
        #pragma unroll
        for (int j = 0; j < 8; ++j) {
          int row = ch * 8 + j;
          *(unsigned short*)(smV + row * 128 + ((2 * k) ^ ((row & 7) << 4))) = vv[j];
        }
      }
    }
    __syncthreads();

    if (k0 > qw0 + 15) continue;  // fully masked for this wave

    // QK^T
    f32x4 sc[4] = {};
    #pragma unroll
    for (int kt = 0; kt < 4; ++kt) {
      #pragma unroll
      for (int ks = 0; ks < 2; ++ks) {
        int row = kt * 16 + lr;
        bf16x8 kb = *(const bf16x8*)(smK + row * 128 + (((ks * 64) + 16 * lg) ^ ((row & 7) << 4)));
        sc[kt] = __builtin_amdgcn_mfma_f32_16x16x32_bf16(qf[ks], kb, sc[kt], 0, 0, 0);
      }
    }

    // causal mask near diagonal
    if (k0 + 63 > qw0) {
      #pragma unroll
      for (int kt = 0; kt < 4; ++kt) {
        int kc = k0 + kt * 16 + lr;
        #pragma unroll
        for (int r = 0; r < 4; ++r)
          if (kc > qw0 + lg * 4 + r) sc[kt][r] = -1e30f;
      }
    }

    // online softmax (rows across 16-lane groups)
    float mnew[4], alpha[4];
    #pragma unroll
    for (int r = 0; r < 4; ++r) {
      float v = fmaxf(fmaxf(sc[0][r], sc[1][r]), fmaxf(sc[2][r], sc[3][r]));
      #pragma unroll
      for (int off = 1; off < 16; off <<= 1) v = fmaxf(v, __shfl_xor(v, off));
      mnew[r] = fmaxf(mrun[r], v);
      alpha[r] = __expf(mrun[r] - mnew[r]);
      mrun[r] = mnew[r];
    }
    #pragma unroll
    for (int r = 0; r < 4; ++r) {
      float s = 0.f;
      #pragma unroll
      for (int kt = 0; kt < 4; ++kt) {
        float p = __expf(sc[kt][r] - mnew[r]);
        sc[kt][r] = p;
        s += p;
      }
      #pragma unroll
      for (int off = 1; off < 16; off <<= 1) s += __shfl_xor(s, off);
      lrun[r] = lrun[r] * alpha[r] + s;
    }

    // write P (wave-private rows), rescale O
    #pragma unroll
    for (int kt = 0; kt < 4; ++kt)
      #pragma unroll
      for (int r = 0; r < 4; ++r) {
        int row = w * 16 + lg * 4 + r;
        *(unsigned short*)(smP + row * 128 + ((2 * (kt * 16 + lr)) ^ ((row & 7) << 4))) =
            f2bf(sc[kt][r]);
      }
    #pragma unroll
    for (int dt = 0; dt < 4; ++dt)
      #pragma unroll
      for (int r = 0; r < 4; ++r) acc_o[dt][r] *= alpha[r];

    // PV
    bf16x8 pa[2];
    #pragma unroll
    for (int ks = 0; ks < 2; ++ks) {
      int row = w * 16 + lr;
      pa[ks] = *(const bf16x8*)(smP + row * 128 + (((ks * 64) + 16 * lg) ^ ((lr & 7) << 4)));
    }
    #pragma unroll
    for (int dt = 0; dt < 4; ++dt) {
      #pragma unroll
      for (int ks = 0; ks < 2; ++ks) {
        int row = dt * 16 + lr;
        bf16x8 vb = *(const bf16x8*)(smV + row * 128 + (((ks * 64) + 16 * lg) ^ ((row & 7) << 4)));
        acc_o[dt] = __builtin_amdgcn_mfma_f32_16x16x32_bf16(pa[ks], vb, acc_o[dt], 0, 0, 0);
      }
    }
  }

  float inv[4];
  #pragma unroll
  for (int r = 0; r < 4; ++r) inv[r] = 1.0f / lrun[r];
  #pragma unroll
  for (int dt = 0; dt < 4; ++dt)
    #pragma unroll
    for (int r = 0; r < 4; ++r)
      attn_out[(size_t)(b * S_ + qw0 + lg * 4 + r) * D_ + h * DH_ + dt * 16 + lr] =
          f2bf(acc_o[dt][r] * inv[r]);
}

extern "C" void kernel_launch(void* const* d_in, const int* in_sizes, int n_in,
                              void* d_out, int out_size, void* d_ws, size_t ws_size,
                              hipStream_t stream) {
  const float* x     = (const float*)d_in[0];
  const float* W_qkv = (const float*)d_in[1];
  const float* b_qkv = (const float*)d_in[2];
  const float* W_out = (const float*)d_in[3];
  const float* b_out = (const float*)d_in[4];
  float* out = (float*)d_out;

  char* ws = (char*)d_ws;
  unsigned short* qkv_bf  = (unsigned short*)ws;                 ws += (size_t)M_ * QKV_LD * 2;  // 25.2 MB
  unsigned short* attn_bf = (unsigned short*)ws;                 ws += (size_t)M_ * D_ * 2;      // 8.4 MB
  unsigned short* x_bf    = (unsigned short*)ws;                 ws += (size_t)M_ * D_ * 2;      // 8.4 MB
  unsigned short* wqkvT   = (unsigned short*)ws;                 ws += (size_t)QKV_LD * D_ * 2;  // 6.3 MB
  unsigned short* woutT   = (unsigned short*)ws;                                                  // 2.1 MB

  dim3 blk(256);
  // prep
  conv_bf16<<<(M_ * D_ / 4 + 255) / 256, blk, 0, stream>>>(x, x_bf, M_ * D_ / 4);
  transpose_bf16<<<dim3(QKV_LD / 32, D_ / 32), blk, 0, stream>>>(W_qkv, wqkvT, D_, QKV_LD);
  transpose_bf16<<<dim3(D_ / 32, D_ / 32), blk, 0, stream>>>(W_out, woutT, D_, D_);
  // 1) QKV projection (bf16 out)
  gemm_bf16_tn<unsigned short><<<dim3(QKV_LD / 128, M_ / 128), blk, 0, stream>>>(
      x_bf, wqkvT, b_qkv, qkv_bf, QKV_LD, D_);
  // 2) causal attention (bf16 in/out)
  attn_fwd_mfma<<<dim3(S_ / 64, B_ * H_), blk, 0, stream>>>(qkv_bf, attn_bf);
  // 3) output projection (fp32 out)
  gemm_bf16_tn<float><<<dim3(D_ / 128, M_ / 128), blk, 0, stream>>>(
      attn_bf, woutT, b_out, out, D_, D_);
}

// Round 5
// 187.679 us; speedup vs baseline: 10.7548x; 1.1201x over previous
//
#include <hip/hip_runtime.h>
#include <hip/hip_bf16.h>

#define B_  2
#define S_  2048
#define D_  1024
#define H_  16
#define DH_ 64
#define M_  (B_ * S_)       // 4096
#define QKV_LD (3 * D_)     // 3072

typedef __bf16 bf16x8 __attribute__((ext_vector_type(8)));
typedef float  f32x4  __attribute__((ext_vector_type(4)));
typedef unsigned short us4 __attribute__((ext_vector_type(4)));
typedef unsigned short us8 __attribute__((ext_vector_type(8)));

__device__ inline unsigned short f2bf(float f) {
  union { __bf16 h; unsigned short u; } cv; cv.h = (__bf16)f; return cv.u;
}
__device__ inline float bf2f(unsigned short u) {
  union { unsigned int i; float f; } cv; cv.i = ((unsigned int)u) << 16; return cv.f;
}
// typed stores: bf16 does the BIT conversion (round-3 bug: (unsigned short)v
// was an int conversion -> output was all-zero)
__device__ inline void cstore(float* p, float v) { *p = v; }
__device__ inline void cstore(unsigned short* p, float v) { *p = f2bf(v); }

__device__ inline void gload_lds16(const void* g, void* lds) {
  __builtin_amdgcn_global_load_lds(
      (const __attribute__((address_space(1))) unsigned int*)g,
      (__attribute__((address_space(3))) unsigned int*)lds, 16, 0, 0);
}

// ---------------- prep: fp32 -> bf16 (row-major copy) ----------------
__global__ __launch_bounds__(256) void conv_bf16(const float* __restrict__ in,
                                                 unsigned short* __restrict__ out, int n4) {
  int i = blockIdx.x * 256 + threadIdx.x;
  if (i >= n4) return;
  float4 v = ((const float4*)in)[i];
  us4 p = { f2bf(v.x), f2bf(v.y), f2bf(v.z), f2bf(v.w) };
  ((us4*)out)[i] = p;
}

// ---------------- prep: fp32 [K][N] -> bf16 [N][K] transpose ----------------
__global__ __launch_bounds__(256) void transpose_bf16(const float* __restrict__ W,
                                                      unsigned short* __restrict__ Wt,
                                                      int K, int N) {
  __shared__ float tile[32][33];
  const int t = threadIdx.x, tx = t & 31, ty = t >> 5;  // ty 0..7
  const int c0 = blockIdx.x * 32, r0 = blockIdx.y * 32;
  #pragma unroll
  for (int i = 0; i < 4; ++i)
    tile[ty + 8 * i][tx] = W[(size_t)(r0 + ty + 8 * i) * N + c0 + tx];
  __syncthreads();
  #pragma unroll
  for (int i = 0; i < 4; ++i)
    Wt[(size_t)(c0 + ty + 8 * i) * K + r0 + tx] = f2bf(tile[tx][ty + 8 * i]);
}

// ---------------- bf16 MFMA GEMM (m97 structure) ----------------
// C[M,N] = A[M,K] @ Bt[N,K]^T + bias.  128x128 tile, BK=32, 4 waves.
template<typename CT>
__global__ __launch_bounds__(256) void gemm_bf16_tn(
    const unsigned short* __restrict__ A,   // [M][K] bf16
    const unsigned short* __restrict__ Bt,  // [N][K] bf16
    const float* __restrict__ bias,
    CT* __restrict__ C, int N, int K) {
  __shared__ __align__(16) unsigned short smA[128 * 32];
  __shared__ __align__(16) unsigned short smB[128 * 32];
  const int t = threadIdx.x;
  const int w = t >> 6, l = t & 63;
  const int lg = l >> 4, lr = l & 15;
  const int row0 = blockIdx.y * 128, col0 = blockIdx.x * 128;
  const int wm = (w >> 1) * 64, wn = (w & 1) * 64;

  f32x4 acc[4][4] = {};

  for (int k0 = 0; k0 < K; k0 += 32) {
    __syncthreads();  // previous iteration's fragment reads complete
    #pragma unroll
    for (int i = 0; i < 2; ++i) {
      const int inst = 2 * w + i;
      const int r = inst * 16 + (l >> 2);
      const int cb = (l & 3) * 8;  // k-chunk of 8 bf16
      gload_lds16(A  + (size_t)(row0 + r) * K + k0 + cb, &smA[inst * 512]);
      gload_lds16(Bt + (size_t)(col0 + r) * K + k0 + cb, &smB[inst * 512]);
    }
    __syncthreads();  // waits vmcnt(0): tiles resident

    bf16x8 af[4], bfr[4];
    #pragma unroll
    for (int m = 0; m < 4; ++m)
      af[m] = *(const bf16x8*)&smA[(wm + m * 16 + lr) * 32 + lg * 8];
    #pragma unroll
    for (int n = 0; n < 4; ++n)
      bfr[n] = *(const bf16x8*)&smB[(wn + n * 16 + lr) * 32 + lg * 8];
    #pragma unroll
    for (int m = 0; m < 4; ++m)
      #pragma unroll
      for (int n = 0; n < 4; ++n)
        acc[m][n] = __builtin_amdgcn_mfma_f32_16x16x32_bf16(af[m], bfr[n], acc[m][n], 0, 0, 0);
  }

  #pragma unroll
  for (int m = 0; m < 4; ++m) {
    #pragma unroll
    for (int n = 0; n < 4; ++n) {
      const int col = col0 + wn + n * 16 + lr;
      const float bv = bias[col];
      #pragma unroll
      for (int r = 0; r < 4; ++r) {
        const int row = row0 + wm + m * 16 + lg * 4 + r;
        cstore(&C[(size_t)row * N + col], acc[m][n][r] + bv);
      }
    }
  }
}

// ---------------- Causal flash attention, bf16 MFMA ----------------
// Q-block 128 rows (4 waves x 32), KVBLK 64, LDS double-buffered, 1 barrier/tile.
__global__ __launch_bounds__(256) void attn_fwd_mfma(
    const unsigned short* __restrict__ qkv, unsigned short* __restrict__ attn_out) {
  const int bh = blockIdx.y;
  const int b = bh / H_, h = bh % H_;
  const int q0 = blockIdx.x * 128;
  const unsigned short* base = qkv + (size_t)b * S_ * QKV_LD;

  __shared__ __align__(16) char smK[2][64 * 128];  // K tile [k][d], XOR-swizzled
  __shared__ __align__(16) char smV[2][64 * 128];  // V^T tile [d][k]
  __shared__ __align__(16) char smP[128 * 128];    // P [q][k], wave-private rows

  const int t  = threadIdx.x;
  const int w  = t >> 6;
  const int l  = t & 63;
  const int lg = l >> 4;
  const int lr = l & 15;
  const int qw0 = q0 + w * 32;   // wave owns rows qw0..qw0+31

  const unsigned short* kbase = base + D_ + h * DH_;
  const unsigned short* vbase = base + 2 * D_ + h * DH_;

  // ---- Q fragments (pre-scaled by 1/8): 2 row-halves x 2 k-chunks ----
  bf16x8 qf[2][2];
  #pragma unroll
  for (int m = 0; m < 2; ++m) {
    const unsigned short* qp = base + (size_t)(qw0 + m * 16 + lr) * QKV_LD + h * DH_ + 8 * lg;
    #pragma unroll
    for (int ks = 0; ks < 2; ++ks) {
      us8 qv = *(const us8*)(qp + 32 * ks);
      #pragma unroll
      for (int e = 0; e < 8; ++e) qf[m][ks][e] = (__bf16)(bf2f(qv[e]) * 0.125f);
    }
  }

  float mrun[2][4], lrun[2][4];
  f32x4 acc_o[2][4] = {};
  #pragma unroll
  for (int m = 0; m < 2; ++m)
    #pragma unroll
    for (int r = 0; r < 4; ++r) { mrun[m][r] = -1e30f; lrun[m][r] = 0.f; }

  // staging registers (T14 async split: issue early, LDS-write late)
  us8 kreg[2], vreg[2];
  const int kp  = (t & 31) * 2;    // V: pair of k-columns
  const int vd0 = (t >> 5) * 8;    // V: 8 d-rows

  auto issue_loads = [&](int k0) {
    #pragma unroll
    for (int it = 0; it < 2; ++it) {
      int idx = t + it * 256;
      int r = idx >> 3, c = idx & 7;
      kreg[it] = *(const us8*)(kbase + (size_t)(k0 + r) * QKV_LD + c * 8);
    }
    vreg[0] = *(const us8*)(vbase + (size_t)(k0 + kp) * QKV_LD + vd0);
    vreg[1] = *(const us8*)(vbase + (size_t)(k0 + kp + 1) * QKV_LD + vd0);
  };
  auto write_lds = [&](int buf) {
    #pragma unroll
    for (int it = 0; it < 2; ++it) {
      int idx = t + it * 256;
      int r = idx >> 3, c = idx & 7;
      *(us8*)(smK[buf] + r * 128 + ((c * 16) ^ ((r & 7) << 4))) = kreg[it];
    }
    #pragma unroll
    for (int j = 0; j < 8; ++j) {
      int row = vd0 + j;
      unsigned int pv = (unsigned int)vreg[0][j] | ((unsigned int)vreg[1][j] << 16);
      *(unsigned int*)(smV[buf] + row * 128 + ((2 * kp) ^ ((row & 7) << 4))) = pv;
    }
  };

  const int ntiles = 2 * blockIdx.x + 2;  // k tiles covering k <= q0+127
  issue_loads(0);
  write_lds(0);
  __syncthreads();

  for (int kti = 0; kti < ntiles; ++kti) {
    const int k0 = kti * 64;
    const int cur = kti & 1;

    if (kti + 1 < ntiles) issue_loads((kti + 1) * 64);

    if (k0 <= qw0 + 31) {  // wave not fully masked
      // ---- K fragments (shared across both row-halves) ----
      bf16x8 kb[4][2];
      #pragma unroll
      for (int kt = 0; kt < 4; ++kt)
        #pragma unroll
        for (int ks = 0; ks < 2; ++ks) {
          int row = kt * 16 + lr;
          kb[kt][ks] = *(const bf16x8*)(smK[cur] + row * 128 +
                                        (((ks * 64) + 16 * lg) ^ ((row & 7) << 4)));
        }
      // ---- QK^T ----
      f32x4 sc[2][4] = {};
      #pragma unroll
      for (int m = 0; m < 2; ++m)
        #pragma unroll
        for (int kt = 0; kt < 4; ++kt)
          #pragma unroll
          for (int ks = 0; ks < 2; ++ks)
            sc[m][kt] = __builtin_amdgcn_mfma_f32_16x16x32_bf16(qf[m][ks], kb[kt][ks], sc[m][kt], 0, 0, 0);

      // ---- causal mask near diagonal ----
      if (k0 + 63 > qw0) {
        #pragma unroll
        for (int m = 0; m < 2; ++m)
          #pragma unroll
          for (int kt = 0; kt < 4; ++kt) {
            int kc = k0 + kt * 16 + lr;
            #pragma unroll
            for (int r = 0; r < 4; ++r)
              if (kc > qw0 + m * 16 + lg * 4 + r) sc[m][kt][r] = -1e30f;
          }
      }

      // ---- online softmax ----
      #pragma unroll
      for (int m = 0; m < 2; ++m) {
        float mnew[4], alpha[4];
        #pragma unroll
        for (int r = 0; r < 4; ++r) {
          float v = fmaxf(fmaxf(sc[m][0][r], sc[m][1][r]), fmaxf(sc[m][2][r], sc[m][3][r]));
          #pragma unroll
          for (int off = 1; off < 16; off <<= 1) v = fmaxf(v, __shfl_xor(v, off));
          mnew[r] = fmaxf(mrun[m][r], v);
          alpha[r] = __expf(mrun[m][r] - mnew[r]);
          mrun[m][r] = mnew[r];
        }
        #pragma unroll
        for (int r = 0; r < 4; ++r) {
          float s = 0.f;
          #pragma unroll
          for (int kt = 0; kt < 4; ++kt) {
            float p = __expf(sc[m][kt][r] - mnew[r]);
            sc[m][kt][r] = p;
            s += p;
          }
          #pragma unroll
          for (int off = 1; off < 16; off <<= 1) s += __shfl_xor(s, off);
          lrun[m][r] = lrun[m][r] * alpha[r] + s;
        }
        // write P (wave-private rows), rescale O
        #pragma unroll
        for (int kt = 0; kt < 4; ++kt)
          #pragma unroll
          for (int r = 0; r < 4; ++r) {
            int row = w * 32 + m * 16 + lg * 4 + r;
            *(unsigned short*)(smP + row * 128 + ((2 * (kt * 16 + lr)) ^ ((row & 7) << 4))) =
                f2bf(sc[m][kt][r]);
          }
        #pragma unroll
        for (int dt = 0; dt < 4; ++dt)
          #pragma unroll
          for (int r = 0; r < 4; ++r) acc_o[m][dt][r] *= alpha[r];
      }

      // ---- PV ----
      bf16x8 pa[2][2];
      #pragma unroll
      for (int m = 0; m < 2; ++m)
        #pragma unroll
        for (int ks = 0; ks < 2; ++ks) {
          int row = w * 32 + m * 16 + lr;
          pa[m][ks] = *(const bf16x8*)(smP + row * 128 +
                                       (((ks * 64) + 16 * lg) ^ ((row & 7) << 4)));
        }
      #pragma unroll
      for (int dt = 0; dt < 4; ++dt) {
        #pragma unroll
        for (int ks = 0; ks < 2; ++ks) {
          int row = dt * 16 + lr;
          bf16x8 vb = *(const bf16x8*)(smV[cur] + row * 128 +
                                       (((ks * 64) + 16 * lg) ^ ((row & 7) << 4)));
          #pragma unroll
          for (int m = 0; m < 2; ++m)
            acc_o[m][dt] = __builtin_amdgcn_mfma_f32_16x16x32_bf16(pa[m][ks], vb, acc_o[m][dt], 0, 0, 0);
        }
      }
    }

    if (kti + 1 < ntiles) write_lds(cur ^ 1);  // buf cur^1 free since last barrier
    __syncthreads();
  }

  // ---- normalize and write out (bf16) ----
  #pragma unroll
  for (int m = 0; m < 2; ++m) {
    float inv[4];
    #pragma unroll
    for (int r = 0; r < 4; ++r) inv[r] = 1.0f / lrun[m][r];
    #pragma unroll
    for (int dt = 0; dt < 4; ++dt)
      #pragma unroll
      for (int r = 0; r < 4; ++r)
        attn_out[(size_t)(b * S_ + qw0 + m * 16 + lg * 4 + r) * D_ + h * DH_ + dt * 16 + lr] =
            f2bf(acc_o[m][dt][r] * inv[r]);
  }
}

extern "C" void kernel_launch(void* const* d_in, const int* in_sizes, int n_in,
                              void* d_out, int out_size, void* d_ws, size_t ws_size,
                              hipStream_t stream) {
  const float* x     = (const float*)d_in[0];
  const float* W_qkv = (const float*)d_in[1];
  const float* b_qkv = (const float*)d_in[2];
  const float* W_out = (const float*)d_in[3];
  const float* b_out = (const float*)d_in[4];
  float* out = (float*)d_out;

  char* ws = (char*)d_ws;
  unsigned short* qkv_bf  = (unsigned short*)ws;                 ws += (size_t)M_ * QKV_LD * 2;
  unsigned short* attn_bf = (unsigned short*)ws;                 ws += (size_t)M_ * D_ * 2;
  unsigned short* x_bf    = (unsigned short*)ws;                 ws += (size_t)M_ * D_ * 2;
  unsigned short* wqkvT   = (unsigned short*)ws;                 ws += (size_t)QKV_LD * D_ * 2;
  unsigned short* woutT   = (unsigned short*)ws;

  dim3 blk(256);
  conv_bf16<<<(M_ * D_ / 4 + 255) / 256, blk, 0, stream>>>(x, x_bf, M_ * D_ / 4);
  transpose_bf16<<<dim3(QKV_LD / 32, D_ / 32), blk, 0, stream>>>(W_qkv, wqkvT, D_, QKV_LD);
  transpose_bf16<<<dim3(D_ / 32, D_ / 32), blk, 0, stream>>>(W_out, woutT, D_, D_);
  gemm_bf16_tn<unsigned short><<<dim3(QKV_LD / 128, M_ / 128), blk, 0, stream>>>(
      x_bf, wqkvT, b_qkv, qkv_bf, QKV_LD, D_);
  attn_fwd_mfma<<<dim3(S_ / 128, B_ * H_), blk, 0, stream>>>(qkv_bf, attn_bf);
  gemm_bf16_tn<float><<<dim3(D_ / 128, M_ / 128), blk, 0, stream>>>(
      attn_bf, woutT, b_out, out, D_, D_);
}

// Round 6
// 148.621 us; speedup vs baseline: 13.5811x; 1.2628x over previous
//
#include <hip/hip_runtime.h>
#include <hip/hip_bf16.h>

#define B_  2
#define S_  2048
#define D_  1024
#define H_  16
#define DH_ 64
#define M_  (B_ * S_)       // 4096
#define QKV_LD (3 * D_)     // 3072

typedef __bf16 bf16x8 __attribute__((ext_vector_type(8)));
typedef float  f32x4  __attribute__((ext_vector_type(4)));
typedef unsigned short us4 __attribute__((ext_vector_type(4)));
typedef unsigned short us8 __attribute__((ext_vector_type(8)));

__device__ inline unsigned short f2bf(float f) {
  union { __bf16 h; unsigned short u; } cv; cv.h = (__bf16)f; return cv.u;
}
__device__ inline float bf2f(unsigned short u) {
  union { unsigned int i; float f; } cv; cv.i = ((unsigned int)u) << 16; return cv.f;
}
// typed stores: bf16 does the BIT conversion (round-3 bug: (unsigned short)v
// was an int conversion -> output was all-zero)
__device__ inline void cstore(float* p, float v) { *p = v; }
__device__ inline void cstore(unsigned short* p, float v) { *p = f2bf(v); }

__device__ inline void gload_lds16(const void* g, void* lds) {
  __builtin_amdgcn_global_load_lds(
      (const __attribute__((address_space(1))) unsigned int*)g,
      (__attribute__((address_space(3))) unsigned int*)lds, 16, 0, 0);
}

// ---------------- prep: fp32 -> bf16 (row-major copy) ----------------
__global__ __launch_bounds__(256) void conv_bf16(const float* __restrict__ in,
                                                 unsigned short* __restrict__ out, int n4) {
  int i = blockIdx.x * 256 + threadIdx.x;
  if (i >= n4) return;
  float4 v = ((const float4*)in)[i];
  us4 p = { f2bf(v.x), f2bf(v.y), f2bf(v.z), f2bf(v.w) };
  ((us4*)out)[i] = p;
}

// ---------------- prep: fp32 [K][N] -> bf16 [N][K] transpose ----------------
__global__ __launch_bounds__(256) void transpose_bf16(const float* __restrict__ W,
                                                      unsigned short* __restrict__ Wt,
                                                      int K, int N) {
  __shared__ float tile[32][33];
  const int t = threadIdx.x, tx = t & 31, ty = t >> 5;  // ty 0..7
  const int c0 = blockIdx.x * 32, r0 = blockIdx.y * 32;
  #pragma unroll
  for (int i = 0; i < 4; ++i)
    tile[ty + 8 * i][tx] = W[(size_t)(r0 + ty + 8 * i) * N + c0 + tx];
  __syncthreads();
  #pragma unroll
  for (int i = 0; i < 4; ++i)
    Wt[(size_t)(c0 + ty + 8 * i) * K + r0 + tx] = f2bf(tile[tx][ty + 8 * i]);
}

// ---------------- bf16 MFMA GEMM (m97 structure) ----------------
// C[M,N] = A[M,K] @ Bt[N,K]^T + bias.  128x128 tile, BK=32, 4 waves.
template<typename CT>
__global__ __launch_bounds__(256) void gemm_bf16_tn(
    const unsigned short* __restrict__ A,   // [M][K] bf16
    const unsigned short* __restrict__ Bt,  // [N][K] bf16
    const float* __restrict__ bias,
    CT* __restrict__ C, int N, int K) {
  __shared__ __align__(16) unsigned short smA[128 * 32];
  __shared__ __align__(16) unsigned short smB[128 * 32];
  const int t = threadIdx.x;
  const int w = t >> 6, l = t & 63;
  const int lg = l >> 4, lr = l & 15;
  const int row0 = blockIdx.y * 128, col0 = blockIdx.x * 128;
  const int wm = (w >> 1) * 64, wn = (w & 1) * 64;

  f32x4 acc[4][4] = {};

  for (int k0 = 0; k0 < K; k0 += 32) {
    __syncthreads();  // previous iteration's fragment reads complete
    #pragma unroll
    for (int i = 0; i < 2; ++i) {
      const int inst = 2 * w + i;
      const int r = inst * 16 + (l >> 2);
      const int cb = (l & 3) * 8;  // k-chunk of 8 bf16
      gload_lds16(A  + (size_t)(row0 + r) * K + k0 + cb, &smA[inst * 512]);
      gload_lds16(Bt + (size_t)(col0 + r) * K + k0 + cb, &smB[inst * 512]);
    }
    __syncthreads();  // waits vmcnt(0): tiles resident

    bf16x8 af[4], bfr[4];
    #pragma unroll
    for (int m = 0; m < 4; ++m)
      af[m] = *(const bf16x8*)&smA[(wm + m * 16 + lr) * 32 + lg * 8];
    #pragma unroll
    for (int n = 0; n < 4; ++n)
      bfr[n] = *(const bf16x8*)&smB[(wn + n * 16 + lr) * 32 + lg * 8];
    #pragma unroll
    for (int m = 0; m < 4; ++m)
      #pragma unroll
      for (int n = 0; n < 4; ++n)
        acc[m][n] = __builtin_amdgcn_mfma_f32_16x16x32_bf16(af[m], bfr[n], acc[m][n], 0, 0, 0);
  }

  #pragma unroll
  for (int m = 0; m < 4; ++m) {
    #pragma unroll
    for (int n = 0; n < 4; ++n) {
      const int col = col0 + wn + n * 16 + lr;
      const float bv = bias[col];
      #pragma unroll
      for (int r = 0; r < 4; ++r) {
        const int row = row0 + wm + m * 16 + lg * 4 + r;
        cstore(&C[(size_t)row * N + col], acc[m][n][r] + bv);
      }
    }
  }
}

// ---------------- Causal flash attention, bf16 MFMA ----------------
// Balanced pairing: block x processes q-tiles x and 31-x (64 rows each) so
// every block does exactly 33 k-tile units. 4 waves x 16 q-rows; KVBLK=64;
// LDS double-buffered K/V, T14 async staging, 1 barrier/tile.
__global__ __launch_bounds__(256) void attn_fwd_mfma(
    const unsigned short* __restrict__ qkv, unsigned short* __restrict__ attn_out) {
  const int bh = blockIdx.y;
  const int b = bh / H_, h = bh % H_;
  const unsigned short* base = qkv + (size_t)b * S_ * QKV_LD;

  __shared__ __align__(16) char smK[2][64 * 128];  // K tile [k][d], XOR-swizzled
  __shared__ __align__(16) char smV[2][64 * 128];  // V^T tile [d][k]
  __shared__ __align__(16) char smP[64 * 128];     // P [q][k], wave-private rows

  const int t  = threadIdx.x;
  const int w  = t >> 6;
  const int l  = t & 63;
  const int lg = l >> 4;
  const int lr = l & 15;

  const unsigned short* kbase = base + D_ + h * DH_;
  const unsigned short* vbase = base + 2 * D_ + h * DH_;

  // staging registers (T14 async split: issue early, LDS-write late)
  us8 kreg[2], vreg[2];
  const int kp  = (t & 31) * 2;    // V: pair of k-columns
  const int vd0 = (t >> 3) & ~7;   // == (t>>5)*8 for 256 threads? no: keep explicit
  const int vdb = (t >> 5) * 8;    // V: 8 d-rows

  auto issue_loads = [&](int k0) {
    #pragma unroll
    for (int it = 0; it < 2; ++it) {
      int idx = t + it * 256;
      int r = idx >> 3, c = idx & 7;
      kreg[it] = *(const us8*)(kbase + (size_t)(k0 + r) * QKV_LD + c * 8);
    }
    vreg[0] = *(const us8*)(vbase + (size_t)(k0 + kp) * QKV_LD + vdb);
    vreg[1] = *(const us8*)(vbase + (size_t)(k0 + kp + 1) * QKV_LD + vdb);
  };
  auto write_lds = [&](int buf) {
    #pragma unroll
    for (int it = 0; it < 2; ++it) {
      int idx = t + it * 256;
      int r = idx >> 3, c = idx & 7;
      *(us8*)(smK[buf] + r * 128 + ((c * 16) ^ ((r & 7) << 4))) = kreg[it];
    }
    #pragma unroll
    for (int j = 0; j < 8; ++j) {
      int row = vdb + j;
      unsigned int pv = (unsigned int)vreg[0][j] | ((unsigned int)vreg[1][j] << 16);
      *(unsigned int*)(smV[buf] + row * 128 + ((2 * kp) ^ ((row & 7) << 4))) = pv;
    }
  };

  #pragma unroll 1
  for (int sel = 0; sel < 2; ++sel) {
    const int qt = sel ? (31 - (int)blockIdx.x) : (int)blockIdx.x;
    const int q0 = qt * 64;
    const int qw0 = q0 + w * 16;   // wave owns rows qw0..qw0+15

    // ---- Q fragments (pre-scaled by 1/8) ----
    bf16x8 qf[2];
    {
      const unsigned short* qp = base + (size_t)(qw0 + lr) * QKV_LD + h * DH_ + 8 * lg;
      #pragma unroll
      for (int ks = 0; ks < 2; ++ks) {
        us8 qv = *(const us8*)(qp + 32 * ks);
        #pragma unroll
        for (int e = 0; e < 8; ++e) qf[ks][e] = (__bf16)(bf2f(qv[e]) * 0.125f);
      }
    }

    float mrun[4], lrun[4];
    f32x4 acc_o[4] = {};
    #pragma unroll
    for (int r = 0; r < 4; ++r) { mrun[r] = -1e30f; lrun[r] = 0.f; }

    const int ntiles = qt + 1;  // k tiles covering k <= q0+63
    issue_loads(0);
    write_lds(0);
    __syncthreads();

    for (int kti = 0; kti < ntiles; ++kti) {
      const int k0 = kti * 64;
      const int cur = kti & 1;

      if (kti + 1 < ntiles) issue_loads((kti + 1) * 64);

      if (k0 <= qw0 + 15) {  // wave not fully masked
        // ---- QK^T ----
        f32x4 sc[4] = {};
        #pragma unroll
        for (int kt = 0; kt < 4; ++kt)
          #pragma unroll
          for (int ks = 0; ks < 2; ++ks) {
            int row = kt * 16 + lr;
            bf16x8 kb = *(const bf16x8*)(smK[cur] + row * 128 +
                                         (((ks * 64) + 16 * lg) ^ ((row & 7) << 4)));
            sc[kt] = __builtin_amdgcn_mfma_f32_16x16x32_bf16(qf[ks], kb, sc[kt], 0, 0, 0);
          }

        // ---- causal mask near diagonal ----
        if (k0 + 63 > qw0) {
          #pragma unroll
          for (int kt = 0; kt < 4; ++kt) {
            int kc = k0 + kt * 16 + lr;
            #pragma unroll
            for (int r = 0; r < 4; ++r)
              if (kc > qw0 + lg * 4 + r) sc[kt][r] = -1e30f;
          }
        }

        // ---- online softmax (rows across 16-lane groups) ----
        float mnew[4], alpha[4];
        #pragma unroll
        for (int r = 0; r < 4; ++r) {
          float v = fmaxf(fmaxf(sc[0][r], sc[1][r]), fmaxf(sc[2][r], sc[3][r]));
          #pragma unroll
          for (int off = 1; off < 16; off <<= 1) v = fmaxf(v, __shfl_xor(v, off));
          mnew[r] = fmaxf(mrun[r], v);
          alpha[r] = __expf(mrun[r] - mnew[r]);
          mrun[r] = mnew[r];
        }
        #pragma unroll
        for (int r = 0; r < 4; ++r) {
          float s = 0.f;
          #pragma unroll
          for (int kt = 0; kt < 4; ++kt) {
            float p = __expf(sc[kt][r] - mnew[r]);
            sc[kt][r] = p;
            s += p;
          }
          #pragma unroll
          for (int off = 1; off < 16; off <<= 1) s += __shfl_xor(s, off);
          lrun[r] = lrun[r] * alpha[r] + s;
        }

        // ---- write P (wave-private rows), rescale O ----
        #pragma unroll
        for (int kt = 0; kt < 4; ++kt)
          #pragma unroll
          for (int r = 0; r < 4; ++r) {
            int row = w * 16 + lg * 4 + r;
            *(unsigned short*)(smP + row * 128 + ((2 * (kt * 16 + lr)) ^ ((row & 7) << 4))) =
                f2bf(sc[kt][r]);
          }
        #pragma unroll
        for (int dt = 0; dt < 4; ++dt)
          #pragma unroll
          for (int r = 0; r < 4; ++r) acc_o[dt][r] *= alpha[r];

        // ---- PV ----
        bf16x8 pa[2];
        #pragma unroll
        for (int ks = 0; ks < 2; ++ks) {
          int row = w * 16 + lr;
          pa[ks] = *(const bf16x8*)(smP + row * 128 +
                                    (((ks * 64) + 16 * lg) ^ ((row & 7) << 4)));
        }
        #pragma unroll
        for (int dt = 0; dt < 4; ++dt)
          #pragma unroll
          for (int ks = 0; ks < 2; ++ks) {
            int row = dt * 16 + lr;
            bf16x8 vb = *(const bf16x8*)(smV[cur] + row * 128 +
                                         (((ks * 64) + 16 * lg) ^ ((row & 7) << 4)));
            acc_o[dt] = __builtin_amdgcn_mfma_f32_16x16x32_bf16(pa[ks], vb, acc_o[dt], 0, 0, 0);
          }
      }

      if (kti + 1 < ntiles) write_lds(cur ^ 1);  // buf cur^1 free since last barrier
      __syncthreads();
    }

    // ---- normalize and write out (bf16) ----
    float inv[4];
    #pragma unroll
    for (int r = 0; r < 4; ++r) inv[r] = 1.0f / lrun[r];
    #pragma unroll
    for (int dt = 0; dt < 4; ++dt)
      #pragma unroll
      for (int r = 0; r < 4; ++r)
        attn_out[(size_t)(b * S_ + qw0 + lg * 4 + r) * D_ + h * DH_ + dt * 16 + lr] =
            f2bf(acc_o[dt][r] * inv[r]);
  }
}

extern "C" void kernel_launch(void* const* d_in, const int* in_sizes, int n_in,
                              void* d_out, int out_size, void* d_ws, size_t ws_size,
                              hipStream_t stream) {
  const float* x     = (const float*)d_in[0];
  const float* W_qkv = (const float*)d_in[1];
  const float* b_qkv = (const float*)d_in[2];
  const float* W_out = (const float*)d_in[3];
  const float* b_out = (const float*)d_in[4];
  float* out = (float*)d_out;

  char* ws = (char*)d_ws;
  unsigned short* qkv_bf  = (unsigned short*)ws;                 ws += (size_t)M_ * QKV_LD * 2;
  unsigned short* attn_bf = (unsigned short*)ws;                 ws += (size_t)M_ * D_ * 2;
  unsigned short* x_bf    = (unsigned short*)ws;                 ws += (size_t)M_ * D_ * 2;
  unsigned short* wqkvT   = (unsigned short*)ws;                 ws += (size_t)QKV_LD * D_ * 2;
  unsigned short* woutT   = (unsigned short*)ws;

  dim3 blk(256);
  conv_bf16<<<(M_ * D_ / 4 + 255) / 256, blk, 0, stream>>>(x, x_bf, M_ * D_ / 4);
  transpose_bf16<<<dim3(QKV_LD / 32, D_ / 32), blk, 0, stream>>>(W_qkv, wqkvT, D_, QKV_LD);
  transpose_bf16<<<dim3(D_ / 32, D_ / 32), blk, 0, stream>>>(W_out, woutT, D_, D_);
  gemm_bf16_tn<unsigned short><<<dim3(QKV_LD / 128, M_ / 128), blk, 0, stream>>>(
      x_bf, wqkvT, b_qkv, qkv_bf, QKV_LD, D_);
  // balanced causal pairing: block x handles q-tiles x and 31-x
  attn_fwd_mfma<<<dim3(S_ / 64 / 2, B_ * H_), blk, 0, stream>>>(qkv_bf, attn_bf);
  gemm_bf16_tn<float><<<dim3(D_ / 128, M_ / 128), blk, 0, stream>>>(
      attn_bf, woutT, b_out, out, D_, D_);
}